// Round 23
// baseline (281.349 us; speedup 1.0000x reference)
//
#include <hip/hip_runtime.h>

// Disable implicit FP contraction: pairwise e^2/z^2 sums must round each
// product individually (numpy semantics). Explicit __fmaf_rn still fuses.
#pragma clang fp contract(off)

// VQ-VAE VectorQuantizer, two-tier, 3 kernels:
//  vq_pack_cb: ebh bf16 [ksub][code][8] + fp32 ETP[d4][code] + np-e2 (ws).
//  vq_gemm: 1024 blocks = 512 row-tiles x 2 code-halves; 3-deep LDS ring,
//    raw s_barrier + counted s_waitcnt vmcnt(4) (R18-proven). Per-half
//    top-2 candidates {s1,s2,i1} stored INSIDE each row's quantized slot
//    (out[row*256 + half*3 + 0..2]) -- R22 lesson: block-local cand makes
//    the combine fusible into rescueq with zero cross-block races.
//  vq_rescueq (512 blocks x 128 rows): P1 merge halves (local, exact
//    first-occurrence tie-break) -> qidx/flags in LDS + loss partial;
//    P2 batch-rescue flagged rows 8-at-a-time (R6-exact np arithmetic,
//    ETP-coalesced; RB=16->8 halves wasted FMA at avg 8.4 flagged/block);
//    P3 idx write + quantized gather-write; last block writes loss
//    (done-counter + threadfence).
// Out (f32): [0..16777215] quantized_st, [16777216] loss, [16777217..] idx.

#define NROWS   65536
#define DDIM    256
#define KCODES  1024
#define QSIZE   (NROWS * DDIM)
#define LOSS_OFF QSIZE
#define IDX_OFF (QSIZE + 1)
#define MARGIN  3.0e-4f
#define RB      8

typedef __bf16 bf16x8 __attribute__((ext_vector_type(8)));
typedef float f32x4 __attribute__((ext_vector_type(4)));
typedef unsigned int u32;
typedef unsigned long long u64;
typedef unsigned short u16;

#define GLOAD_LDS16(gsrc, ldst) \
    __builtin_amdgcn_global_load_lds( \
        (const __attribute__((address_space(1))) u32*)(gsrc), \
        (__attribute__((address_space(3))) u32*)(ldst), 16, 0, 0)

__device__ __forceinline__ u32 omap(float s) {
    u32 u = __float_as_uint(s);
    return (u & 0x80000000u) ? ~u : (u | 0x80000000u);
}
__device__ __forceinline__ u64 pack_key(float s, u32 j) {
    return ((u64)omap(s) << 32) | j;
}

// numpy pairwise sum-of-squares over 128 floats (unrolled-8 path)
__device__ __forceinline__ float pw128_sq(const float* __restrict__ x) {
    float r[8];
    #pragma unroll
    for (int j = 0; j < 8; ++j) r[j] = x[j] * x[j];
    for (int i = 8; i < 128; i += 8)
        #pragma unroll
        for (int j = 0; j < 8; ++j) r[j] += x[i + j] * x[i + j];
    return ((r[0] + r[1]) + (r[2] + r[3])) + ((r[4] + r[5]) + (r[6] + r[7]));
}

// ---- codebook prep: ebh bf16 [ksub][code][8], fp32 ETP[d4][code], np-e2 ----
__global__ __launch_bounds__(256) void vq_pack_cb(
    const float* __restrict__ E, u16* __restrict__ ebh,
    float4* __restrict__ etp,
    float* __restrict__ ee, float* __restrict__ sum, int* __restrict__ done) {
    int j = blockIdx.x * 256 + threadIdx.x;
    if (j == 0) { *sum = 0.0f; *done = 0; }
    if (j >= KCODES) return;
    const float* row = E + (size_t)j * DDIM;
    const float4* row4 = (const float4*)row;
    #pragma unroll
    for (int d4 = 0; d4 < DDIM / 4; ++d4) etp[d4 * KCODES + j] = row4[d4];
    #pragma unroll
    for (int ks = 0; ks < 32; ++ks) {
        bf16x8 h8;
        #pragma unroll
        for (int e = 0; e < 8; ++e) h8[e] = (__bf16)row[ks * 8 + e];
        *(bf16x8*)(ebh + ((size_t)ks * KCODES + j) * 8) = h8;
    }
    ee[j] = pw128_sq(row) + pw128_sq(row + 128);
}

// ---- tier-1 MFMA GEMM, code-split, counted-vmcnt 3-deep pipeline ----
__device__ __forceinline__ void stage_chunk32(
    const u16* __restrict__ ebh, int codebase, char* buf, int t) {
    // 32 codes x 32 ksubs x 16B = 16KB; lane-linear LDS (p*16).
    // EXACTLY 4 global_load_lds per lane (vmcnt accounting relies on this).
    #pragma unroll
    for (int i = 0; i < 4; ++i) {
        int p = t + 256 * i;
        int ks = p >> 5, c = p & 31;
        GLOAD_LDS16(ebh + ((size_t)ks * KCODES + codebase + c) * 8, buf + p * 16);
    }
}

__global__ __launch_bounds__(256, 4) void vq_gemm(
    const float* __restrict__ Z,
    const u16* __restrict__ ebh,
    const float* __restrict__ ee,
    float* __restrict__ out, float* __restrict__ sum) {
    __shared__ __align__(16) char bs[3][16384];   // 3-deep B chunk ring
    const int t = threadIdx.x, w = t >> 6, l = t & 63;
    const int lr = l & 15, lg = l >> 4;
    const int rowtile = blockIdx.x >> 1, half = blockIdx.x & 1;
    const int rowbase = rowtile * 128;
    const int codebase = half * 512;

    // A fragments: load fp32 from Z, convert to bf16 in regs; Sum z^2 (half 0).
    bf16x8 aH[2][8];
    float ss = 0.0f;
    #pragma unroll
    for (int rf = 0; rf < 2; ++rf) {
        const float* zr = Z + (size_t)(rowbase + w * 32 + rf * 16 + lr) * DDIM;
        #pragma unroll
        for (int s = 0; s < 8; ++s) {
            const float4* src = (const float4*)(zr + (s * 4 + lg) * 8);
            float4 v0 = src[0], v1 = src[1];
            bf16x8 h8;
            h8[0] = (__bf16)v0.x; h8[1] = (__bf16)v0.y;
            h8[2] = (__bf16)v0.z; h8[3] = (__bf16)v0.w;
            h8[4] = (__bf16)v1.x; h8[5] = (__bf16)v1.y;
            h8[6] = (__bf16)v1.z; h8[7] = (__bf16)v1.w;
            aH[rf][s] = h8;
            ss += v0.x * v0.x + v0.y * v0.y + v0.z * v0.z + v0.w * v0.w
                + v1.x * v1.x + v1.y * v1.y + v1.z * v1.z + v1.w * v1.w;
        }
    }
    if (half == 0) {
        #pragma unroll
        for (int off = 1; off < 64; off <<= 1) ss += __shfl_xor(ss, off);
        if (l == 0) atomicAdd(sum, ss);
    }

    float s1[2][4], s2[2][4]; int i1[2][4];
    #pragma unroll
    for (int rf = 0; rf < 2; ++rf)
        #pragma unroll
        for (int r = 0; r < 4; ++r) { s1[rf][r] = 1e30f; s2[rf][r] = 1e30f; i1[rf][r] = 0x7FFFFFFF; }

    // prologue: 2 chunks in flight
    stage_chunk32(ebh, codebase, bs[0], t);
    stage_chunk32(ebh, codebase + 32, bs[1], t);
    for (int ch = 0; ch < 16; ++ch) {
        // wait: chunk ch complete (4 newest loads = chunk ch+1 may still fly)
        if (ch < 15) { asm volatile("s_waitcnt vmcnt(4)" ::: "memory"); }
        else         { asm volatile("s_waitcnt vmcnt(0)" ::: "memory"); }
        __builtin_amdgcn_sched_barrier(0);
        __builtin_amdgcn_s_barrier();     // raw barrier: no vmcnt(0) drain
        if (ch + 2 < 16) stage_chunk32(ebh, codebase + (ch + 2) * 32, bs[(ch + 2) % 3], t);
        const char* buf = bs[ch % 3];
        const int chbase = codebase + ch * 32;

        f32x4 acc[2][2];
        #pragma unroll
        for (int rf = 0; rf < 2; ++rf)
            #pragma unroll
            for (int cf = 0; cf < 2; ++cf) acc[rf][cf] = 0.0f;

        #pragma unroll
        for (int s = 0; s < 8; ++s) {
            #pragma unroll
            for (int cf = 0; cf < 2; ++cf) {
                int off = (((s * 4 + lg) * 32 + cf * 16 + lr) * 16);
                bf16x8 bh = *(const bf16x8*)(buf + off);
                #pragma unroll
                for (int rf = 0; rf < 2; ++rf)
                    acc[rf][cf] = __builtin_amdgcn_mfma_f32_16x16x32_bf16(aH[rf][s], bh, acc[rf][cf], 0, 0, 0);
            }
        }
        // epilogue: float top-2 (s2 via min/max median trick), codes ascending
        #pragma unroll
        for (int cf = 0; cf < 2; ++cf) {
            int code = chbase + cf * 16 + lr;
            float e2c = ee[code];
            #pragma unroll
            for (int rf = 0; rf < 2; ++rf)
                #pragma unroll
                for (int r = 0; r < 4; ++r) {
                    float v = __fmaf_rn(-2.0f, acc[rf][cf][r], e2c);
                    float so = s1[rf][r];
                    s2[rf][r] = fminf(fmaxf(so, v), s2[rf][r]);  // median(so,s2,v)
                    bool lt = v < so;
                    s1[rf][r] = lt ? v : so;
                    i1[rf][r] = lt ? code : i1[rf][r];
                }
        }
    }
    // butterfly across the 16 lanes of each row group (lr bits only)
    #pragma unroll
    for (int off = 1; off < 16; off <<= 1) {
        #pragma unroll
        for (int rf = 0; rf < 2; ++rf)
            #pragma unroll
            for (int r = 0; r < 4; ++r) {
                float os1 = __shfl_xor(s1[rf][r], off);
                float os2 = __shfl_xor(s2[rf][r], off);
                int   oi  = __shfl_xor(i1[rf][r], off);
                float ns2 = fminf(fmaxf(s1[rf][r], os1), fminf(s2[rf][r], os2));
                bool take = (os1 < s1[rf][r]) || (os1 == s1[rf][r] && oi < i1[rf][r]);
                s1[rf][r] = take ? os1 : s1[rf][r];
                i1[rf][r] = take ? oi : i1[rf][r];
                s2[rf][r] = ns2;
            }
    }
    // write per-half candidates INSIDE each row's quantized slot:
    // out[row*256 + half*3 + {0,1,2}] = {s1, s2, i1}
    if (lr == 0) {
        #pragma unroll
        for (int rf = 0; rf < 2; ++rf)
            #pragma unroll
            for (int r = 0; r < 4; ++r) {
                size_t row = (size_t)rowbase + w * 32 + rf * 16 + lg * 4 + r;
                float* c = out + row * DDIM + half * 3;
                c[0] = s1[rf][r];
                c[1] = s2[rf][r];
                c[2] = (float)i1[rf][r];
            }
    }
}

// ---- fused combine + rescue + qwrite: 512 blocks x 128 rows ----
__global__ __launch_bounds__(256) void vq_rescueq(
    const float* __restrict__ Z, const float4* __restrict__ etp,
    const float* __restrict__ ee, const float* __restrict__ E,
    float* __restrict__ sum, int* __restrict__ done, float* __restrict__ out) {
    __shared__ float zrow[RB][DDIM];    // 8 KB
    __shared__ float zacc[RB][16];
    __shared__ float z2s[RB];
    __shared__ u64 rmin[RB];
    __shared__ int qidx[128];
    __shared__ int fl[128];
    __shared__ int nfl;
    const int t = threadIdx.x;
    const int b = blockIdx.x;
    const int rowbase = b * 128;

    if (t == 0) nfl = 0;
    __syncthreads();

    // ---- P1: combine halves for this block's 128 rows (local, race-free) ----
    if (t < 128) {
        const float* c = out + (size_t)(rowbase + t) * DDIM;
        float s1a = c[0], s2a = c[1]; int ia = (int)c[2];
        float s1b = c[3], s2b = c[4]; int ib = (int)c[5];
        // half0 codes (0-511) all < half1: strict < keeps first-occurrence
        bool tb = s1b < s1a;
        float s1 = tb ? s1b : s1a;
        int   i1 = tb ? ib : ia;
        float s2 = tb ? fminf(s2b, s1a) : fminf(s2a, s1b);
        qidx[t] = i1;
        if (s2 <= s1 + MARGIN) { int s = atomicAdd(&nfl, 1); fl[s] = t; }
        // loss partial (any order OK)
        #pragma unroll
        for (int off = 1; off < 64; off <<= 1) s1 += __shfl_xor(s1, off);
        if ((t & 63) == 0) atomicAdd(sum, s1);
    }
    __syncthreads();
    const int n = nfl;

    // ---- P2: batch-rescue flagged rows, RB=8 at a time (R6-exact np) ----
    for (int start = 0; start < n; start += RB) {
        int nb = n - start; if (nb > RB) nb = RB;
        if (t < RB) rmin[t] = ~0ULL;
        __syncthreads();
        // stage z rows (coalesced float4): nb rows x 64 float4
        #pragma unroll
        for (int i = 0; i < RB * (DDIM / 4) / 256; ++i) {
            int p = t + 256 * i;
            int r = p >> 6, c4 = p & 63;
            if (r < nb) ((float4*)zrow[r])[c4] =
                ((const float4*)(Z + (size_t)(rowbase + fl[start + r]) * DDIM))[c4];
        }
        __syncthreads();
        // np pairwise z2 per row
        if (t < RB * 8) {
            int r = t >> 3, j = t & 7;
            const float* zr = zrow[r];
            float a0 = zr[j] * zr[j], a1 = zr[128 + j] * zr[128 + j];
            for (int i = 8; i < 128; i += 8) {
                a0 += zr[i + j] * zr[i + j];
                a1 += zr[128 + i + j] * zr[128 + i + j];
            }
            zacc[r][j] = a0; zacc[r][8 + j] = a1;
        }
        __syncthreads();
        if (t < RB) {
            const float* a = zacc[t];
            float c0 = ((a[0] + a[1]) + (a[2] + a[3])) + ((a[4] + a[5]) + (a[6] + a[7]));
            float c1 = ((a[8] + a[9]) + (a[10] + a[11])) + ((a[12] + a[13]) + (a[14] + a[15]));
            z2s[t] = c0 + c1;
        }
        __syncthreads();
        // strict sequential fp32 FMA chain, k ascending (ETP coalesced)
        float acc[4][RB];
        #pragma unroll
        for (int c = 0; c < 4; ++c)
            #pragma unroll
            for (int r = 0; r < RB; ++r) acc[c][r] = 0.0f;
        for (int d4 = 0; d4 < DDIM / 4; ++d4) {
            float4 ev[4];
            #pragma unroll
            for (int c = 0; c < 4; ++c)
                ev[c] = etp[(size_t)d4 * KCODES + t + c * 256];
            #pragma unroll
            for (int r = 0; r < RB; ++r) {
                float4 zv = ((const float4*)zrow[r])[d4];
                #pragma unroll
                for (int c = 0; c < 4; ++c) {
                    float a = acc[c][r];
                    a = __fmaf_rn(zv.x, ev[c].x, a); a = __fmaf_rn(zv.y, ev[c].y, a);
                    a = __fmaf_rn(zv.z, ev[c].z, a); a = __fmaf_rn(zv.w, ev[c].w, a);
                    acc[c][r] = a;
                }
            }
        }
        // per-row argmin: np full-magnitude combine + first-min tie-break
        float e2c[4];
        #pragma unroll
        for (int c = 0; c < 4; ++c) e2c[c] = ee[t + c * 256];
        #pragma unroll
        for (int r = 0; r < RB; ++r) {
            float zr2 = z2s[r];
            u64 best = ~0ULL;
            #pragma unroll
            for (int c = 0; c < 4; ++c) {
                float d = (zr2 + e2c[c]) - 2.0f * acc[c][r];
                u64 k = pack_key(d, (u32)(t + c * 256));
                if (k < best) best = k;
            }
            #pragma unroll
            for (int off = 1; off < 64; off <<= 1) {
                u64 o = __shfl_xor(best, off);
                if (o < best) best = o;
            }
            if ((t & 63) == 0) atomicMin(&rmin[r], best);
        }
        __syncthreads();
        if (t < nb) qidx[fl[start + t]] = (int)(u32)(rmin[t] & 0xFFFFFFFFu);
        __syncthreads();
    }

    // ---- P3: final idx write + quantized gather-write (128 KB contiguous) ----
    if (t < 128) out[(size_t)IDX_OFF + rowbase + t] = (float)qidx[t];
    float4* outq = (float4*)out;
    #pragma unroll
    for (int k = 0; k < 32; ++k) {
        int p = t + 256 * k;
        int r = p >> 6, c4 = p & 63;
        int code = qidx[r];
        outq[(size_t)rowbase * 64 + p] = ((const float4*)(E + (size_t)code * DDIM))[c4];
    }

    // ---- loss: last block to finish writes it (sum adds fenced-before) ----
    __threadfence();
    __syncthreads();
    if (t == 0) {
        int pos = __hip_atomic_fetch_add(done, 1, __ATOMIC_ACQ_REL,
                                         __HIP_MEMORY_SCOPE_AGENT);
        if (pos == (int)gridDim.x - 1) {
            float s = __hip_atomic_load(sum, __ATOMIC_RELAXED,
                                        __HIP_MEMORY_SCOPE_AGENT);
            out[LOSS_OFF] = 1.25f * s / (float)QSIZE;
        }
    }
}

extern "C" void kernel_launch(void* const* d_in, const int* in_sizes, int n_in,
                              void* d_out, int out_size, void* d_ws, size_t ws_size,
                              hipStream_t stream) {
    const float* Z; const float* E;
    if (in_sizes[0] == QSIZE) { Z = (const float*)d_in[0]; E = (const float*)d_in[1]; }
    else                      { Z = (const float*)d_in[1]; E = (const float*)d_in[0]; }
    float* out = (float*)d_out;
    char* ws = (char*)d_ws;

    float*  sum  = (float*)ws;                         // @0
    int*    done = (int*)(ws + 8);                     // @8
    float*  ee   = (float*)(ws + 1024);                // 4 KB
    u16*    ebh  = (u16*)(ws + 8192);                  // 512 KB -> 532480
    float4* etp  = (float4*)(ws + 532480);             // 1 MB   -> ~1.55 MB total

    vq_pack_cb<<<4, 256, 0, stream>>>(E, ebh, etp, ee, sum, done);
    vq_gemm<<<NROWS / 128 * 2, 256, 0, stream>>>(Z, ebh, ee, out, sum);
    vq_rescueq<<<NROWS / 128, 256, 0, stream>>>(Z, etp, ee, E, sum, done, out);
}

// Round 24
// 216.681 us; speedup vs baseline: 1.2984x; 1.2984x over previous
//
#include <hip/hip_runtime.h>

// Disable implicit FP contraction: pairwise e^2/z^2 sums must round each
// product individually (numpy semantics). Explicit __fmaf_rn still fuses.
#pragma clang fp contract(off)

// VQ-VAE VectorQuantizer, two-tier, 4 kernels (R22-proven structure; R23
// lesson: fusing combine into rescueq via cand-in-row-slot created a
// scattered-read stall phase -> 176us; kernel-boundary combine stays).
//  vq_pack_cb: ebh bf16 [ksub][code][8] (ws) + fp32 ETP[d4][code] (ws) + e2.
//  vq_gemm: 1024 blocks = 512 row-tiles x 2 code-halves; 3-deep LDS ring,
//    raw s_barrier + counted s_waitcnt vmcnt(4) (R18-proven, ~78us).
//    Per-half float top-2 -> cand arrays in q-region scratch.
//  vq_combine: merge halves per row (exact first-occurrence tie-break),
//    write idx, loss partial, flags[row] (ws byte array).
//  vq_rescueq (fused rescue+qwrite, 512 blocks x 128 rows): block-local
//    flagged rows batch-rescued RB=8-at-a-time (R6-exact np arithmetic,
//    ETP-coalesced; R23 change kept: avg 8.4 flagged/block -> RB=8 halves
//    wasted FMA slots vs 16), idx patched in LDS, quantized gather-write.
// Out (f32): [0..16777215] quantized_st, [16777216] loss, [16777217..] idx.

#define NROWS   65536
#define DDIM    256
#define KCODES  1024
#define QSIZE   (NROWS * DDIM)
#define LOSS_OFF QSIZE
#define IDX_OFF (QSIZE + 1)
#define MARGIN  3.0e-4f
#define RBATCH  8

typedef __bf16 bf16x8 __attribute__((ext_vector_type(8)));
typedef float f32x4 __attribute__((ext_vector_type(4)));
typedef unsigned int u32;
typedef unsigned long long u64;
typedef unsigned short u16;
typedef unsigned char u8;

#define GLOAD_LDS16(gsrc, ldst) \
    __builtin_amdgcn_global_load_lds( \
        (const __attribute__((address_space(1))) u32*)(gsrc), \
        (__attribute__((address_space(3))) u32*)(ldst), 16, 0, 0)

__device__ __forceinline__ u32 omap(float s) {
    u32 u = __float_as_uint(s);
    return (u & 0x80000000u) ? ~u : (u | 0x80000000u);
}
__device__ __forceinline__ u64 pack_key(float s, u32 j) {
    return ((u64)omap(s) << 32) | j;
}

// numpy pairwise sum-of-squares over 128 floats (unrolled-8 path)
__device__ __forceinline__ float pw128_sq(const float* __restrict__ x) {
    float r[8];
    #pragma unroll
    for (int j = 0; j < 8; ++j) r[j] = x[j] * x[j];
    for (int i = 8; i < 128; i += 8)
        #pragma unroll
        for (int j = 0; j < 8; ++j) r[j] += x[i + j] * x[i + j];
    return ((r[0] + r[1]) + (r[2] + r[3])) + ((r[4] + r[5]) + (r[6] + r[7]));
}

// ---- codebook prep: ebh bf16 [ksub][code][8], fp32 ETP[d4][code], np-e2 ----
__global__ __launch_bounds__(256) void vq_pack_cb(
    const float* __restrict__ E, u16* __restrict__ ebh,
    float4* __restrict__ etp,
    float* __restrict__ ee, float* __restrict__ sum) {
    int j = blockIdx.x * 256 + threadIdx.x;
    if (j == 0) *sum = 0.0f;
    if (j >= KCODES) return;
    const float* row = E + (size_t)j * DDIM;
    const float4* row4 = (const float4*)row;
    #pragma unroll
    for (int d4 = 0; d4 < DDIM / 4; ++d4) etp[d4 * KCODES + j] = row4[d4];
    #pragma unroll
    for (int ks = 0; ks < 32; ++ks) {
        bf16x8 h8;
        #pragma unroll
        for (int e = 0; e < 8; ++e) h8[e] = (__bf16)row[ks * 8 + e];
        *(bf16x8*)(ebh + ((size_t)ks * KCODES + j) * 8) = h8;
    }
    ee[j] = pw128_sq(row) + pw128_sq(row + 128);
}

// ---- tier-1 MFMA GEMM, code-split, counted-vmcnt 3-deep pipeline ----
__device__ __forceinline__ void stage_chunk32(
    const u16* __restrict__ ebh, int codebase, char* buf, int t) {
    // 32 codes x 32 ksubs x 16B = 16KB; lane-linear LDS (p*16).
    // EXACTLY 4 global_load_lds per lane (vmcnt accounting relies on this).
    #pragma unroll
    for (int i = 0; i < 4; ++i) {
        int p = t + 256 * i;
        int ks = p >> 5, c = p & 31;
        GLOAD_LDS16(ebh + ((size_t)ks * KCODES + codebase + c) * 8, buf + p * 16);
    }
}

__global__ __launch_bounds__(256, 4) void vq_gemm(
    const float* __restrict__ Z,
    const u16* __restrict__ ebh,
    const float* __restrict__ ee,
    float* __restrict__ s1c, float* __restrict__ s2c, float* __restrict__ i1c,
    float* __restrict__ sum) {
    __shared__ __align__(16) char bs[3][16384];   // 3-deep B chunk ring
    const int t = threadIdx.x, w = t >> 6, l = t & 63;
    const int lr = l & 15, lg = l >> 4;
    const int rowtile = blockIdx.x >> 1, half = blockIdx.x & 1;
    const int rowbase = rowtile * 128;
    const int codebase = half * 512;

    // A fragments: load fp32 from Z, convert to bf16 in regs; Sum z^2 (half 0).
    bf16x8 aH[2][8];
    float ss = 0.0f;
    #pragma unroll
    for (int rf = 0; rf < 2; ++rf) {
        const float* zr = Z + (size_t)(rowbase + w * 32 + rf * 16 + lr) * DDIM;
        #pragma unroll
        for (int s = 0; s < 8; ++s) {
            const float4* src = (const float4*)(zr + (s * 4 + lg) * 8);
            float4 v0 = src[0], v1 = src[1];
            bf16x8 h8;
            h8[0] = (__bf16)v0.x; h8[1] = (__bf16)v0.y;
            h8[2] = (__bf16)v0.z; h8[3] = (__bf16)v0.w;
            h8[4] = (__bf16)v1.x; h8[5] = (__bf16)v1.y;
            h8[6] = (__bf16)v1.z; h8[7] = (__bf16)v1.w;
            aH[rf][s] = h8;
            ss += v0.x * v0.x + v0.y * v0.y + v0.z * v0.z + v0.w * v0.w
                + v1.x * v1.x + v1.y * v1.y + v1.z * v1.z + v1.w * v1.w;
        }
    }
    if (half == 0) {
        #pragma unroll
        for (int off = 1; off < 64; off <<= 1) ss += __shfl_xor(ss, off);
        if (l == 0) atomicAdd(sum, ss);
    }

    float s1[2][4], s2[2][4]; int i1[2][4];
    #pragma unroll
    for (int rf = 0; rf < 2; ++rf)
        #pragma unroll
        for (int r = 0; r < 4; ++r) { s1[rf][r] = 1e30f; s2[rf][r] = 1e30f; i1[rf][r] = 0x7FFFFFFF; }

    // prologue: 2 chunks in flight
    stage_chunk32(ebh, codebase, bs[0], t);
    stage_chunk32(ebh, codebase + 32, bs[1], t);
    for (int ch = 0; ch < 16; ++ch) {
        // wait: chunk ch complete (4 newest loads = chunk ch+1 may still fly)
        if (ch < 15) { asm volatile("s_waitcnt vmcnt(4)" ::: "memory"); }
        else         { asm volatile("s_waitcnt vmcnt(0)" ::: "memory"); }
        __builtin_amdgcn_sched_barrier(0);
        __builtin_amdgcn_s_barrier();     // raw barrier: no vmcnt(0) drain
        if (ch + 2 < 16) stage_chunk32(ebh, codebase + (ch + 2) * 32, bs[(ch + 2) % 3], t);
        const char* buf = bs[ch % 3];
        const int chbase = codebase + ch * 32;

        f32x4 acc[2][2];
        #pragma unroll
        for (int rf = 0; rf < 2; ++rf)
            #pragma unroll
            for (int cf = 0; cf < 2; ++cf) acc[rf][cf] = 0.0f;

        #pragma unroll
        for (int s = 0; s < 8; ++s) {
            #pragma unroll
            for (int cf = 0; cf < 2; ++cf) {
                int off = (((s * 4 + lg) * 32 + cf * 16 + lr) * 16);
                bf16x8 bh = *(const bf16x8*)(buf + off);
                #pragma unroll
                for (int rf = 0; rf < 2; ++rf)
                    acc[rf][cf] = __builtin_amdgcn_mfma_f32_16x16x32_bf16(aH[rf][s], bh, acc[rf][cf], 0, 0, 0);
            }
        }
        // epilogue: float top-2 (s2 via min/max median trick), codes ascending
        #pragma unroll
        for (int cf = 0; cf < 2; ++cf) {
            int code = chbase + cf * 16 + lr;
            float e2c = ee[code];
            #pragma unroll
            for (int rf = 0; rf < 2; ++rf)
                #pragma unroll
                for (int r = 0; r < 4; ++r) {
                    float v = __fmaf_rn(-2.0f, acc[rf][cf][r], e2c);
                    float so = s1[rf][r];
                    s2[rf][r] = fminf(fmaxf(so, v), s2[rf][r]);  // median(so,s2,v)
                    bool lt = v < so;
                    s1[rf][r] = lt ? v : so;
                    i1[rf][r] = lt ? code : i1[rf][r];
                }
        }
    }
    // butterfly across the 16 lanes of each row group (lr bits only)
    #pragma unroll
    for (int off = 1; off < 16; off <<= 1) {
        #pragma unroll
        for (int rf = 0; rf < 2; ++rf)
            #pragma unroll
            for (int r = 0; r < 4; ++r) {
                float os1 = __shfl_xor(s1[rf][r], off);
                float os2 = __shfl_xor(s2[rf][r], off);
                int   oi  = __shfl_xor(i1[rf][r], off);
                float ns2 = fminf(fmaxf(s1[rf][r], os1), fminf(s2[rf][r], os2));
                bool take = (os1 < s1[rf][r]) || (os1 == s1[rf][r] && oi < i1[rf][r]);
                s1[rf][r] = take ? os1 : s1[rf][r];
                i1[rf][r] = take ? oi : i1[rf][r];
                s2[rf][r] = ns2;
            }
    }
    // write per-half candidates (q-region scratch, layout [half][NROWS])
    if (lr == 0) {
        #pragma unroll
        for (int rf = 0; rf < 2; ++rf)
            #pragma unroll
            for (int r = 0; r < 4; ++r) {
                size_t idx = (size_t)half * NROWS + rowbase + w * 32 + rf * 16 + lg * 4 + r;
                s1c[idx] = s1[rf][r];
                s2c[idx] = s2[rf][r];
                i1c[idx] = (float)i1[rf][r];
            }
    }
}

// ---- merge halves: final top-2, idx, loss partial, per-row flag ----
__global__ __launch_bounds__(256) void vq_combine(
    const float* __restrict__ s1c, const float* __restrict__ s2c,
    const float* __restrict__ i1c,
    float* out, float* __restrict__ sum, u8* __restrict__ flags) {
    const int r = blockIdx.x * 256 + threadIdx.x;
    float s1a = s1c[r], s1b = s1c[NROWS + r];
    float s2a = s2c[r], s2b = s2c[NROWS + r];
    int   ia  = (int)i1c[r], ib = (int)i1c[NROWS + r];
    // half0 codes (0-511) all < half1 codes: strict < keeps first-occurrence
    bool tb = s1b < s1a;
    float s1 = tb ? s1b : s1a;
    int   i1 = tb ? ib : ia;
    float s2 = tb ? fminf(s2b, s1a) : fminf(s2a, s1b);
    out[(size_t)IDX_OFF + r] = (float)i1;
    flags[r] = (s2 <= s1 + MARGIN) ? 1 : 0;
    // loss partial (any order OK)
    #pragma unroll
    for (int off = 1; off < 64; off <<= 1) s1 += __shfl_xor(s1, off);
    if ((threadIdx.x & 63) == 0) atomicAdd(sum, s1);
}

// ---- fused rescue + qwrite: 512 blocks x 128 rows. Block-local flagged
//      rows batch-rescued RB=8 at a time (R6-exact np arithmetic, ETP-
//      coalesced), idx patched, quantized gather-write. Block 0: loss. ----
__global__ __launch_bounds__(256) void vq_rescueq(
    const float* __restrict__ Z, const float4* __restrict__ etp,
    const float* __restrict__ ee, const float* __restrict__ E,
    const u8* __restrict__ flags, const float* __restrict__ sum,
    float* out) {
    __shared__ float zrow[RBATCH][DDIM];    // 8 KB
    __shared__ float zacc[RBATCH][16];
    __shared__ float z2s[RBATCH];
    __shared__ u64 rmin[RBATCH];
    __shared__ int qidx[128];
    __shared__ int fl[128];
    __shared__ int nfl;
    const int t = threadIdx.x;
    const int b = blockIdx.x;
    const int rowbase = b * 128;

    if (b == 0 && t == 0) out[LOSS_OFF] = 1.25f * (*sum) / (float)QSIZE;
    if (t == 0) nfl = 0;
    __syncthreads();
    if (t < 128) {
        int code = (int)out[(size_t)IDX_OFF + rowbase + t];
        qidx[t] = code;
        if (flags[rowbase + t]) { int s = atomicAdd(&nfl, 1); fl[s] = t; }
    }
    __syncthreads();
    const int n = nfl;

    for (int start = 0; start < n; start += RBATCH) {
        int nb = n - start; if (nb > RBATCH) nb = RBATCH;
        if (t < RBATCH) rmin[t] = ~0ULL;
        __syncthreads();
        // stage z rows (coalesced float4): nb rows x 64 float4
        #pragma unroll
        for (int i = 0; i < RBATCH * (DDIM / 4) / 256; ++i) {
            int p = t + 256 * i;
            int r = p >> 6, c4 = p & 63;
            if (r < nb) ((float4*)zrow[r])[c4] =
                ((const float4*)(Z + (size_t)(rowbase + fl[start + r]) * DDIM))[c4];
        }
        __syncthreads();
        // np pairwise z2 per row
        if (t < RBATCH * 8) {
            int r = t >> 3, j = t & 7;
            const float* zr = zrow[r];
            float a0 = zr[j] * zr[j], a1 = zr[128 + j] * zr[128 + j];
            for (int i = 8; i < 128; i += 8) {
                a0 += zr[i + j] * zr[i + j];
                a1 += zr[128 + i + j] * zr[128 + i + j];
            }
            zacc[r][j] = a0; zacc[r][8 + j] = a1;
        }
        __syncthreads();
        if (t < RBATCH) {
            const float* a = zacc[t];
            float c0 = ((a[0] + a[1]) + (a[2] + a[3])) + ((a[4] + a[5]) + (a[6] + a[7]));
            float c1 = ((a[8] + a[9]) + (a[10] + a[11])) + ((a[12] + a[13]) + (a[14] + a[15]));
            z2s[t] = c0 + c1;
        }
        __syncthreads();
        // strict sequential fp32 FMA chain, k ascending (ETP coalesced)
        float acc[4][RBATCH];
        #pragma unroll
        for (int c = 0; c < 4; ++c)
            #pragma unroll
            for (int r = 0; r < RBATCH; ++r) acc[c][r] = 0.0f;
        for (int d4 = 0; d4 < DDIM / 4; ++d4) {
            float4 ev[4];
            #pragma unroll
            for (int c = 0; c < 4; ++c)
                ev[c] = etp[(size_t)d4 * KCODES + t + c * 256];
            #pragma unroll
            for (int r = 0; r < RBATCH; ++r) {
                float4 zv = ((const float4*)zrow[r])[d4];
                #pragma unroll
                for (int c = 0; c < 4; ++c) {
                    float a = acc[c][r];
                    a = __fmaf_rn(zv.x, ev[c].x, a); a = __fmaf_rn(zv.y, ev[c].y, a);
                    a = __fmaf_rn(zv.z, ev[c].z, a); a = __fmaf_rn(zv.w, ev[c].w, a);
                    acc[c][r] = a;
                }
            }
        }
        // per-row argmin: np full-magnitude combine + first-min tie-break
        float e2c[4];
        #pragma unroll
        for (int c = 0; c < 4; ++c) e2c[c] = ee[t + c * 256];
        #pragma unroll
        for (int r = 0; r < RBATCH; ++r) {
            float zr2 = z2s[r];
            u64 best = ~0ULL;
            #pragma unroll
            for (int c = 0; c < 4; ++c) {
                float d = (zr2 + e2c[c]) - 2.0f * acc[c][r];
                u64 k = pack_key(d, (u32)(t + c * 256));
                if (k < best) best = k;
            }
            #pragma unroll
            for (int off = 1; off < 64; off <<= 1) {
                u64 o = __shfl_xor(best, off);
                if (o < best) best = o;
            }
            if ((t & 63) == 0) atomicMin(&rmin[r], best);
        }
        __syncthreads();
        if (t < nb) {
            int lrow = fl[start + t];
            int code = (int)(u32)(rmin[t] & 0xFFFFFFFFu);
            out[(size_t)IDX_OFF + rowbase + lrow] = (float)code;
            qidx[lrow] = code;
        }
        __syncthreads();
    }

    // quantized gather-write: 128 rows x 64 float4 (contiguous 128KB)
    float4* outq = (float4*)out;
    #pragma unroll
    for (int k = 0; k < 32; ++k) {
        int p = t + 256 * k;
        int r = p >> 6, c4 = p & 63;
        int code = qidx[r];
        outq[(size_t)rowbase * 64 + p] = ((const float4*)(E + (size_t)code * DDIM))[c4];
    }
}

extern "C" void kernel_launch(void* const* d_in, const int* in_sizes, int n_in,
                              void* d_out, int out_size, void* d_ws, size_t ws_size,
                              hipStream_t stream) {
    const float* Z; const float* E;
    if (in_sizes[0] == QSIZE) { Z = (const float*)d_in[0]; E = (const float*)d_in[1]; }
    else                      { Z = (const float*)d_in[1]; E = (const float*)d_in[0]; }
    float* out = (float*)d_out;
    char* ws = (char*)d_ws;

    float*  sum   = (float*)ws;                        // @0
    float*  ee    = (float*)(ws + 1024);               // 4 KB
    u16*    ebh   = (u16*)(ws + 8192);                 // 512 KB -> 532480
    u8*     flags = (u8*)(ws + 532480);                // 64 KB  -> 598016
    float4* etp   = (float4*)(ws + 598016);            // 1 MB   -> ~1.57 MB total

    // per-half candidate arrays live in the q-output region; they are read
    // only by vq_combine (kernel boundary) before vq_rescueq overwrites them.
    float* s1c = out;                                  // [2][NROWS]
    float* s2c = out + 2 * NROWS;                      // [2][NROWS]
    float* i1c = out + 4 * NROWS;                      // [2][NROWS]

    vq_pack_cb<<<4, 256, 0, stream>>>(E, ebh, etp, ee, sum);
    vq_gemm<<<NROWS / 128 * 2, 256, 0, stream>>>(Z, ebh, ee, s1c, s2c, i1c, sum);
    vq_combine<<<NROWS / 256, 256, 0, stream>>>(s1c, s2c, i1c, out, sum, flags);
    vq_rescueq<<<NROWS / 128, 256, 0, stream>>>(Z, etp, ee, E, flags, sum, out);
}

// Round 25
// 197.844 us; speedup vs baseline: 1.4221x; 1.0952x over previous
//
#include <hip/hip_runtime.h>

// Disable implicit FP contraction: pairwise e^2/z^2 sums must round each
// product individually (numpy semantics). Explicit __fmaf_rn still fuses.
#pragma clang fp contract(off)

// VQ-VAE VectorQuantizer, two-tier, 4 kernels. EXACT R22 configuration --
// the measured best (199.8us). Post-R22 experiments all regressed:
//  R23 (combine fused via cand-in-row-slot): scattered reads -> 281us.
//  R24 (RBATCH 16->8): per-batch fixed ETP-walk cost doubled -> 217us.
//  R20/21 (cooperative fusion): spill / corruption.
// Structure:
//  vq_pack_cb: ebh bf16 [ksub][code][8] (ws) + fp32 ETP[d4][code] (ws) + e2.
//  vq_gemm: 1024 blocks = 512 row-tiles x 2 code-halves; 3-deep LDS ring,
//    raw s_barrier + counted s_waitcnt vmcnt(4) (T3/T4). Per-half float
//    top-2 -> cand arrays in q-region scratch ([half][NROWS], coalesced).
//  vq_combine: merge halves (exact first-occurrence tie-break), idx,
//    loss partial, flags[row].
//  vq_rescueq: fused rescue+qwrite, 512 blocks x 128 rows; block-local
//    flagged rows batch-rescued 16-at-a-time (R6-exact np arithmetic,
//    ETP-coalesced), idx patched in LDS, quantized gather-write.
// Out (f32): [0..16777215] quantized_st, [16777216] loss, [16777217..] idx.

#define NROWS   65536
#define DDIM    256
#define KCODES  1024
#define QSIZE   (NROWS * DDIM)
#define LOSS_OFF QSIZE
#define IDX_OFF (QSIZE + 1)
#define MARGIN  3.0e-4f
#define RBATCH  16

typedef __bf16 bf16x8 __attribute__((ext_vector_type(8)));
typedef float f32x4 __attribute__((ext_vector_type(4)));
typedef unsigned int u32;
typedef unsigned long long u64;
typedef unsigned short u16;
typedef unsigned char u8;

#define GLOAD_LDS16(gsrc, ldst) \
    __builtin_amdgcn_global_load_lds( \
        (const __attribute__((address_space(1))) u32*)(gsrc), \
        (__attribute__((address_space(3))) u32*)(ldst), 16, 0, 0)

__device__ __forceinline__ u32 omap(float s) {
    u32 u = __float_as_uint(s);
    return (u & 0x80000000u) ? ~u : (u | 0x80000000u);
}
__device__ __forceinline__ u64 pack_key(float s, u32 j) {
    return ((u64)omap(s) << 32) | j;
}

// numpy pairwise sum-of-squares over 128 floats (unrolled-8 path)
__device__ __forceinline__ float pw128_sq(const float* __restrict__ x) {
    float r[8];
    #pragma unroll
    for (int j = 0; j < 8; ++j) r[j] = x[j] * x[j];
    for (int i = 8; i < 128; i += 8)
        #pragma unroll
        for (int j = 0; j < 8; ++j) r[j] += x[i + j] * x[i + j];
    return ((r[0] + r[1]) + (r[2] + r[3])) + ((r[4] + r[5]) + (r[6] + r[7]));
}

// ---- codebook prep: ebh bf16 [ksub][code][8], fp32 ETP[d4][code], np-e2 ----
__global__ __launch_bounds__(256) void vq_pack_cb(
    const float* __restrict__ E, u16* __restrict__ ebh,
    float4* __restrict__ etp,
    float* __restrict__ ee, float* __restrict__ sum) {
    int j = blockIdx.x * 256 + threadIdx.x;
    if (j == 0) *sum = 0.0f;
    if (j >= KCODES) return;
    const float* row = E + (size_t)j * DDIM;
    const float4* row4 = (const float4*)row;
    #pragma unroll
    for (int d4 = 0; d4 < DDIM / 4; ++d4) etp[d4 * KCODES + j] = row4[d4];
    #pragma unroll
    for (int ks = 0; ks < 32; ++ks) {
        bf16x8 h8;
        #pragma unroll
        for (int e = 0; e < 8; ++e) h8[e] = (__bf16)row[ks * 8 + e];
        *(bf16x8*)(ebh + ((size_t)ks * KCODES + j) * 8) = h8;
    }
    ee[j] = pw128_sq(row) + pw128_sq(row + 128);
}

// ---- tier-1 MFMA GEMM, code-split, counted-vmcnt 3-deep pipeline ----
__device__ __forceinline__ void stage_chunk32(
    const u16* __restrict__ ebh, int codebase, char* buf, int t) {
    // 32 codes x 32 ksubs x 16B = 16KB; lane-linear LDS (p*16).
    // EXACTLY 4 global_load_lds per lane (vmcnt accounting relies on this).
    #pragma unroll
    for (int i = 0; i < 4; ++i) {
        int p = t + 256 * i;
        int ks = p >> 5, c = p & 31;
        GLOAD_LDS16(ebh + ((size_t)ks * KCODES + codebase + c) * 8, buf + p * 16);
    }
}

__global__ __launch_bounds__(256, 4) void vq_gemm(
    const float* __restrict__ Z,
    const u16* __restrict__ ebh,
    const float* __restrict__ ee,
    float* __restrict__ s1c, float* __restrict__ s2c, float* __restrict__ i1c,
    float* __restrict__ sum) {
    __shared__ __align__(16) char bs[3][16384];   // 3-deep B chunk ring
    const int t = threadIdx.x, w = t >> 6, l = t & 63;
    const int lr = l & 15, lg = l >> 4;
    const int rowtile = blockIdx.x >> 1, half = blockIdx.x & 1;
    const int rowbase = rowtile * 128;
    const int codebase = half * 512;

    // A fragments: load fp32 from Z, convert to bf16 in regs; Sum z^2 (half 0).
    bf16x8 aH[2][8];
    float ss = 0.0f;
    #pragma unroll
    for (int rf = 0; rf < 2; ++rf) {
        const float* zr = Z + (size_t)(rowbase + w * 32 + rf * 16 + lr) * DDIM;
        #pragma unroll
        for (int s = 0; s < 8; ++s) {
            const float4* src = (const float4*)(zr + (s * 4 + lg) * 8);
            float4 v0 = src[0], v1 = src[1];
            bf16x8 h8;
            h8[0] = (__bf16)v0.x; h8[1] = (__bf16)v0.y;
            h8[2] = (__bf16)v0.z; h8[3] = (__bf16)v0.w;
            h8[4] = (__bf16)v1.x; h8[5] = (__bf16)v1.y;
            h8[6] = (__bf16)v1.z; h8[7] = (__bf16)v1.w;
            aH[rf][s] = h8;
            ss += v0.x * v0.x + v0.y * v0.y + v0.z * v0.z + v0.w * v0.w
                + v1.x * v1.x + v1.y * v1.y + v1.z * v1.z + v1.w * v1.w;
        }
    }
    if (half == 0) {
        #pragma unroll
        for (int off = 1; off < 64; off <<= 1) ss += __shfl_xor(ss, off);
        if (l == 0) atomicAdd(sum, ss);
    }

    float s1[2][4], s2[2][4]; int i1[2][4];
    #pragma unroll
    for (int rf = 0; rf < 2; ++rf)
        #pragma unroll
        for (int r = 0; r < 4; ++r) { s1[rf][r] = 1e30f; s2[rf][r] = 1e30f; i1[rf][r] = 0x7FFFFFFF; }

    // prologue: 2 chunks in flight
    stage_chunk32(ebh, codebase, bs[0], t);
    stage_chunk32(ebh, codebase + 32, bs[1], t);
    for (int ch = 0; ch < 16; ++ch) {
        // wait: chunk ch complete (4 newest loads = chunk ch+1 may still fly)
        if (ch < 15) { asm volatile("s_waitcnt vmcnt(4)" ::: "memory"); }
        else         { asm volatile("s_waitcnt vmcnt(0)" ::: "memory"); }
        __builtin_amdgcn_sched_barrier(0);
        __builtin_amdgcn_s_barrier();     // raw barrier: no vmcnt(0) drain
        if (ch + 2 < 16) stage_chunk32(ebh, codebase + (ch + 2) * 32, bs[(ch + 2) % 3], t);
        const char* buf = bs[ch % 3];
        const int chbase = codebase + ch * 32;

        f32x4 acc[2][2];
        #pragma unroll
        for (int rf = 0; rf < 2; ++rf)
            #pragma unroll
            for (int cf = 0; cf < 2; ++cf) acc[rf][cf] = 0.0f;

        #pragma unroll
        for (int s = 0; s < 8; ++s) {
            #pragma unroll
            for (int cf = 0; cf < 2; ++cf) {
                int off = (((s * 4 + lg) * 32 + cf * 16 + lr) * 16);
                bf16x8 bh = *(const bf16x8*)(buf + off);
                #pragma unroll
                for (int rf = 0; rf < 2; ++rf)
                    acc[rf][cf] = __builtin_amdgcn_mfma_f32_16x16x32_bf16(aH[rf][s], bh, acc[rf][cf], 0, 0, 0);
            }
        }
        // epilogue: float top-2 (s2 via min/max median trick), codes ascending
        #pragma unroll
        for (int cf = 0; cf < 2; ++cf) {
            int code = chbase + cf * 16 + lr;
            float e2c = ee[code];
            #pragma unroll
            for (int rf = 0; rf < 2; ++rf)
                #pragma unroll
                for (int r = 0; r < 4; ++r) {
                    float v = __fmaf_rn(-2.0f, acc[rf][cf][r], e2c);
                    float so = s1[rf][r];
                    s2[rf][r] = fminf(fmaxf(so, v), s2[rf][r]);  // median(so,s2,v)
                    bool lt = v < so;
                    s1[rf][r] = lt ? v : so;
                    i1[rf][r] = lt ? code : i1[rf][r];
                }
        }
    }
    // butterfly across the 16 lanes of each row group (lr bits only)
    #pragma unroll
    for (int off = 1; off < 16; off <<= 1) {
        #pragma unroll
        for (int rf = 0; rf < 2; ++rf)
            #pragma unroll
            for (int r = 0; r < 4; ++r) {
                float os1 = __shfl_xor(s1[rf][r], off);
                float os2 = __shfl_xor(s2[rf][r], off);
                int   oi  = __shfl_xor(i1[rf][r], off);
                float ns2 = fminf(fmaxf(s1[rf][r], os1), fminf(s2[rf][r], os2));
                bool take = (os1 < s1[rf][r]) || (os1 == s1[rf][r] && oi < i1[rf][r]);
                s1[rf][r] = take ? os1 : s1[rf][r];
                i1[rf][r] = take ? oi : i1[rf][r];
                s2[rf][r] = ns2;
            }
    }
    // write per-half candidates (q-region scratch, layout [half][NROWS])
    if (lr == 0) {
        #pragma unroll
        for (int rf = 0; rf < 2; ++rf)
            #pragma unroll
            for (int r = 0; r < 4; ++r) {
                size_t idx = (size_t)half * NROWS + rowbase + w * 32 + rf * 16 + lg * 4 + r;
                s1c[idx] = s1[rf][r];
                s2c[idx] = s2[rf][r];
                i1c[idx] = (float)i1[rf][r];
            }
    }
}

// ---- merge halves: final top-2, idx, loss partial, per-row flag ----
__global__ __launch_bounds__(256) void vq_combine(
    const float* __restrict__ s1c, const float* __restrict__ s2c,
    const float* __restrict__ i1c,
    float* out, float* __restrict__ sum, u8* __restrict__ flags) {
    const int r = blockIdx.x * 256 + threadIdx.x;
    float s1a = s1c[r], s1b = s1c[NROWS + r];
    float s2a = s2c[r], s2b = s2c[NROWS + r];
    int   ia  = (int)i1c[r], ib = (int)i1c[NROWS + r];
    // half0 codes (0-511) all < half1 codes: strict < keeps first-occurrence
    bool tb = s1b < s1a;
    float s1 = tb ? s1b : s1a;
    int   i1 = tb ? ib : ia;
    float s2 = tb ? fminf(s2b, s1a) : fminf(s2a, s1b);
    out[(size_t)IDX_OFF + r] = (float)i1;
    flags[r] = (s2 <= s1 + MARGIN) ? 1 : 0;
    // loss partial (any order OK)
    #pragma unroll
    for (int off = 1; off < 64; off <<= 1) s1 += __shfl_xor(s1, off);
    if ((threadIdx.x & 63) == 0) atomicAdd(sum, s1);
}

// ---- fused rescue + qwrite: 512 blocks x 128 rows. Block-local flagged
//      rows batch-rescued 16 at a time (R6-exact np arithmetic, ETP-
//      coalesced), idx patched, quantized gather-write. Block 0: loss. ----
__global__ __launch_bounds__(256) void vq_rescueq(
    const float* __restrict__ Z, const float4* __restrict__ etp,
    const float* __restrict__ ee, const float* __restrict__ E,
    const u8* __restrict__ flags, const float* __restrict__ sum,
    float* out) {
    __shared__ float zrow[RBATCH][DDIM];    // 16 KB
    __shared__ float zacc[RBATCH][16];
    __shared__ float z2s[RBATCH];
    __shared__ u64 rmin[RBATCH];
    __shared__ int qidx[128];
    __shared__ int fl[128];
    __shared__ int nfl;
    const int t = threadIdx.x;
    const int b = blockIdx.x;
    const int rowbase = b * 128;

    if (b == 0 && t == 0) out[LOSS_OFF] = 1.25f * (*sum) / (float)QSIZE;
    if (t == 0) nfl = 0;
    __syncthreads();
    if (t < 128) {
        int code = (int)out[(size_t)IDX_OFF + rowbase + t];
        qidx[t] = code;
        if (flags[rowbase + t]) { int s = atomicAdd(&nfl, 1); fl[s] = t; }
    }
    __syncthreads();
    const int n = nfl;

    for (int start = 0; start < n; start += RBATCH) {
        int nb = n - start; if (nb > RBATCH) nb = RBATCH;
        if (t < RBATCH) rmin[t] = ~0ULL;
        __syncthreads();
        // stage z rows (coalesced float4): nb rows x 64 float4
        #pragma unroll
        for (int i = 0; i < RBATCH * (DDIM / 4) / 256; ++i) {
            int p = t + 256 * i;
            int r = p >> 6, c4 = p & 63;
            if (r < nb) ((float4*)zrow[r])[c4] =
                ((const float4*)(Z + (size_t)(rowbase + fl[start + r]) * DDIM))[c4];
        }
        __syncthreads();
        // np pairwise z2 per row
        if (t < RBATCH * 8) {
            int r = t >> 3, j = t & 7;
            const float* zr = zrow[r];
            float a0 = zr[j] * zr[j], a1 = zr[128 + j] * zr[128 + j];
            for (int i = 8; i < 128; i += 8) {
                a0 += zr[i + j] * zr[i + j];
                a1 += zr[128 + i + j] * zr[128 + i + j];
            }
            zacc[r][j] = a0; zacc[r][8 + j] = a1;
        }
        __syncthreads();
        if (t < RBATCH) {
            const float* a = zacc[t];
            float c0 = ((a[0] + a[1]) + (a[2] + a[3])) + ((a[4] + a[5]) + (a[6] + a[7]));
            float c1 = ((a[8] + a[9]) + (a[10] + a[11])) + ((a[12] + a[13]) + (a[14] + a[15]));
            z2s[t] = c0 + c1;
        }
        __syncthreads();
        // strict sequential fp32 FMA chain, k ascending (ETP coalesced)
        float acc[4][RBATCH];
        #pragma unroll
        for (int c = 0; c < 4; ++c)
            #pragma unroll
            for (int r = 0; r < RBATCH; ++r) acc[c][r] = 0.0f;
        for (int d4 = 0; d4 < DDIM / 4; ++d4) {
            float4 ev[4];
            #pragma unroll
            for (int c = 0; c < 4; ++c)
                ev[c] = etp[(size_t)d4 * KCODES + t + c * 256];
            #pragma unroll
            for (int r = 0; r < RBATCH; ++r) {
                float4 zv = ((const float4*)zrow[r])[d4];
                #pragma unroll
                for (int c = 0; c < 4; ++c) {
                    float a = acc[c][r];
                    a = __fmaf_rn(zv.x, ev[c].x, a); a = __fmaf_rn(zv.y, ev[c].y, a);
                    a = __fmaf_rn(zv.z, ev[c].z, a); a = __fmaf_rn(zv.w, ev[c].w, a);
                    acc[c][r] = a;
                }
            }
        }
        // per-row argmin: np full-magnitude combine + first-min tie-break
        float e2c[4];
        #pragma unroll
        for (int c = 0; c < 4; ++c) e2c[c] = ee[t + c * 256];
        #pragma unroll
        for (int r = 0; r < RBATCH; ++r) {
            float zr2 = z2s[r];
            u64 best = ~0ULL;
            #pragma unroll
            for (int c = 0; c < 4; ++c) {
                float d = (zr2 + e2c[c]) - 2.0f * acc[c][r];
                u64 k = pack_key(d, (u32)(t + c * 256));
                if (k < best) best = k;
            }
            #pragma unroll
            for (int off = 1; off < 64; off <<= 1) {
                u64 o = __shfl_xor(best, off);
                if (o < best) best = o;
            }
            if ((t & 63) == 0) atomicMin(&rmin[r], best);
        }
        __syncthreads();
        if (t < nb) {
            int lrow = fl[start + t];
            int code = (int)(u32)(rmin[t] & 0xFFFFFFFFu);
            out[(size_t)IDX_OFF + rowbase + lrow] = (float)code;
            qidx[lrow] = code;
        }
        __syncthreads();
    }

    // quantized gather-write: 128 rows x 64 float4 (contiguous 128KB)
    float4* outq = (float4*)out;
    #pragma unroll
    for (int k = 0; k < 32; ++k) {
        int p = t + 256 * k;
        int r = p >> 6, c4 = p & 63;
        int code = qidx[r];
        outq[(size_t)rowbase * 64 + p] = ((const float4*)(E + (size_t)code * DDIM))[c4];
    }
}

extern "C" void kernel_launch(void* const* d_in, const int* in_sizes, int n_in,
                              void* d_out, int out_size, void* d_ws, size_t ws_size,
                              hipStream_t stream) {
    const float* Z; const float* E;
    if (in_sizes[0] == QSIZE) { Z = (const float*)d_in[0]; E = (const float*)d_in[1]; }
    else                      { Z = (const float*)d_in[1]; E = (const float*)d_in[0]; }
    float* out = (float*)d_out;
    char* ws = (char*)d_ws;

    float*  sum   = (float*)ws;                        // @0
    float*  ee    = (float*)(ws + 1024);               // 4 KB
    u16*    ebh   = (u16*)(ws + 8192);                 // 512 KB -> 532480
    u8*     flags = (u8*)(ws + 532480);                // 64 KB  -> 598016
    float4* etp   = (float4*)(ws + 598016);            // 1 MB   -> ~1.57 MB total

    // per-half candidate arrays live in the q-output region; they are read
    // only by vq_combine (kernel boundary) before vq_rescueq overwrites them.
    float* s1c = out;                                  // [2][NROWS]
    float* s2c = out + 2 * NROWS;                      // [2][NROWS]
    float* i1c = out + 4 * NROWS;                      // [2][NROWS]

    vq_pack_cb<<<4, 256, 0, stream>>>(E, ebh, etp, ee, sum);
    vq_gemm<<<NROWS / 128 * 2, 256, 0, stream>>>(Z, ebh, ee, s1c, s2c, i1c, sum);
    vq_combine<<<NROWS / 256, 256, 0, stream>>>(s1c, s2c, i1c, out, sum, flags);
    vq_rescueq<<<NROWS / 128, 256, 0, stream>>>(Z, etp, ee, E, flags, sum, out);
}